// Round 10
// baseline (142.547 us; speedup 1.0000x reference)
//
#include <hip/hip_runtime.h>
#include <hip/hip_bf16.h>
#include <stdint.h>

// Problem constants (B,S,D,H,M) = (2,2048,1024,16,64), HD=64
#define B_  2
#define S_  2048
#define D_  1024
#define H_  16
#define HD_ 64
#define M_  64
#define SKM (S_ + M_)   // 2112
#define LOG2E 1.44269504088896340736f

typedef __attribute__((ext_vector_type(8))) short s16x8;
typedef __attribute__((ext_vector_type(4))) float f32x4;
typedef __attribute__((ext_vector_type(16))) float f32x16;

// global_load_lds width=16: linear LDS dest (base + lane*16), per-lane global src
#define GLOAD16(gp, lp) __builtin_amdgcn_global_load_lds( \
    (const __attribute__((address_space(1))) void*)(gp),  \
    (__attribute__((address_space(3))) void*)(lp), 16, 0, 0)

// counted vmcnt wait (T4): literal N, then pin scheduler (rule #18)
#define WAITVM(N) do { asm volatile("s_waitcnt vmcnt(" #N ")" ::: "memory"); \
                       __builtin_amdgcn_sched_barrier(0); } while (0)
// raw s_barrier WITHOUT the __syncthreads vmcnt(0) drain
#define BARRIER() do { asm volatile("" ::: "memory"); \
                       __builtin_amdgcn_s_barrier(); \
                       asm volatile("" ::: "memory"); } while (0)

__device__ __forceinline__ unsigned short f2bf(float f) {
  union { float f; unsigned int u; } v; v.f = f;
  unsigned int r = v.u + 0x7fffu + ((v.u >> 16) & 1u);  // RNE
  return (unsigned short)(r >> 16);
}

__device__ __forceinline__ unsigned pkbf(float lo, float hi) {
  union { __hip_bfloat162 b; unsigned u; } t;
  t.b = __float22bfloat162_rn(make_float2(lo, hi));   // -> v_cvt_pk_bf16_f32
  return t.u;
}

// ---- mask compaction: idx[b][j] = j-th unmasked key, cnt[b] = count ----------
__global__ void compact_mask(const int* __restrict__ mask,
                             int* __restrict__ idx, int* __restrict__ cnt) {
  const int b = blockIdx.x;
  __shared__ int base, wsum[4];
  if (threadIdx.x == 0) base = 0;
  const int lane = threadIdx.x & 63, w = threadIdx.x >> 6;
  __syncthreads();
  for (int c = 0; c < S_; c += 256) {
    int key = c + threadIdx.x;
    int mv = mask[b * S_ + key];
    unsigned long long bal = __ballot(mv != 0);
    int pre = __popcll(bal & ((1ull << lane) - 1ull));
    if (lane == 0) wsum[w] = __popcll(bal);
    __syncthreads();
    int woff = 0;
    for (int i = 0; i < w; i++) woff += wsum[i];
    int tot = wsum[0] + wsum[1] + wsum[2] + wsum[3];
    if (mv) idx[b * S_ + base + woff + pre] = key;
    __syncthreads();
    if (threadIdx.x == 0) base += tot;
    __syncthreads();
  }
  if (threadIdx.x == 0) cnt[b] = base;
}

// ---- query + 4 weight matrices bf16-convert in ONE launch --------------------
// regions: [0, NQ) -> query; [NQ + k*NW, NQ + (k+1)*NW) -> weight k (NW = 2^20)
__global__ void cvt_all(const float* __restrict__ q,
                        const float* __restrict__ w0, const float* __restrict__ w1,
                        const float* __restrict__ w2, const float* __restrict__ w3,
                        unsigned short* __restrict__ qf,
                        unsigned short* __restrict__ o0, unsigned short* __restrict__ o1,
                        unsigned short* __restrict__ o2, unsigned short* __restrict__ o3) {
  size_t i = ((size_t)blockIdx.x * 256 + threadIdx.x) * 4;
  const float* in; unsigned short* out; size_t off;
  const size_t NQs = (size_t)B_ * S_ * D_;
  if (i < NQs) { in = q; out = qf; off = i; }
  else {
    size_t j = i - NQs;
    int wsel = (int)(j >> 20);
    off = j & ((1u << 20) - 1);
    in  = (wsel == 0) ? w0 : (wsel == 1) ? w1 : (wsel == 2) ? w2 : w3;
    out = (wsel == 0) ? o0 : (wsel == 1) ? o1 : (wsel == 2) ? o2 : o3;
  }
  float4 v = *(const float4*)&in[off];
  ushort4 o;
  o.x = f2bf(v.x); o.y = f2bf(v.y); o.z = f2bf(v.z); o.w = f2bf(v.w);
  *(ushort4*)&out[off] = o;
}

// ---- gather-convert key/value rows where mask=1 (one row per block) ----------
__global__ void cvt_kv_gather(const float* __restrict__ key, const float* __restrict__ value,
                              unsigned short* __restrict__ kf, unsigned short* __restrict__ vf,
                              const int* __restrict__ idx, const int* __restrict__ cnt) {
  int b = blockIdx.y, j = blockIdx.x;
  if (j >= cnt[b]) return;
  const float* in = blockIdx.z ? value : key;
  unsigned short* out = blockIdx.z ? vf : kf;
  int src = idx[b * S_ + j];
  const float* ip = in + ((size_t)(b * S_) + src) * D_;
  unsigned short* op = out + ((size_t)(b * S_) + j) * D_;
  int t = threadIdx.x * 4;
  float4 v = *(const float4*)&ip[t];
  ushort4 o;
  o.x = f2bf(v.x); o.y = f2bf(v.y); o.z = f2bf(v.z); o.w = f2bf(v.w);
  *(ushort4*)&op[t] = o;
}

// ---- memory rows appended at key position cnt[b] (AFTER the K/V GEMMs) -------
__global__ void fill_mem(const float* __restrict__ mk, const float* __restrict__ mv,
                         unsigned short* __restrict__ Kb, unsigned short* __restrict__ VtG,
                         const int* __restrict__ cnt) {
  int i = blockIdx.x * 256 + threadIdx.x;     // 0 .. M_*D_-1
  int row = i >> 10, col = i & 1023;
  int hI = col >> 6, dd = col & 63;
  unsigned short kv = f2bf(8.0f * mk[i]);
  unsigned short vv = f2bf(8.0f * mv[i]);
#pragma unroll
  for (int b = 0; b < B_; b++) {
    int c = cnt[b];
    Kb[((size_t)(b * SKM) + c + row) * D_ + col] = kv;
    VtG[((size_t)(b * H_ + hI) * HD_ + dd) * SKM + c + row] = vv;
  }
}

// ------ GEMM core: 64x128 tile (M x N), BK=32, 2-buffer + counted vmcnt -------
// Small M-tile for TLP: 24 KB LDS -> ~5 blocks/CU co-resident; latency hidden
// by block-level parallelism, not pipeline depth (R8 lesson). 3 DMA loads per
// thread per step (A:1, B:2) -> steady-state WAITVM(3).
// Swizzle invariant (rule #21 both-sides): LDS[r][c] = global[r][c ^ ((r>>1)&3)].
__device__ __forceinline__ void gemm_core64(
    const unsigned short* __restrict__ A,
    const unsigned short* __restrict__ Bw,
    unsigned short* As, unsigned short* Bs,   // As: 2*64*32, Bs: 2*128*32
    int mBase, int nBase, int K,
    int tid, f32x4 acc[2][4]) {
  const int lane = tid & 63, w = tid >> 6;
  const int wr = w >> 1, wc = w & 1;
  const int lr = lane & 15, lk = lane >> 4;
  const int srA = tid >> 2, cdA = tid & 3;        // A staging: row 0..63
  const int srB = w * 32 + (lane >> 2), cdB = lane & 3;   // B rows: srB, srB+16
  const int caA = cdA ^ ((srA >> 1) & 3);
  const int NT = K / 32;

#define STAGE_(buf, k0)                                                          \
  {                                                                              \
    GLOAD16(&A[(size_t)(mBase + srA) * K + (k0) + caA * 8],                      \
            &As[(buf) * (64 * 32) + (w * 16) * 32]);                             \
    _Pragma("unroll")                                                            \
    for (int i = 0; i < 2; i++) {                                                \
      int r = srB + i * 16;                                                      \
      int ca = cdB ^ ((r >> 1) & 3);                                             \
      GLOAD16(&Bw[(size_t)(nBase + r) * K + (k0) + ca * 8],                      \
              &Bs[(buf) * (128 * 32) + (w * 32 + i * 16) * 32]);                 \
    }                                                                            \
  }

  STAGE_(0, 0);                              // 3 loads in flight
  int cur = 0;
  for (int t = 0; t < NT; ++t) {
    if (t + 1 < NT) {
      STAGE_(cur ^ 1, (t + 1) * 32);         // 6 in flight
      WAITVM(3);                             // tile t's 3 done; t+1's in flight
    } else {
      WAITVM(0);
    }
    BARRIER();                               // all waves: tile t staged
    s16x8 af[2], bf[4];
#pragma unroll
    for (int mi = 0; mi < 2; mi++) {
      int row = wr * 32 + mi * 16 + lr;
      af[mi] = *(const s16x8*)&As[cur * (64 * 32) + row * 32 + ((lk ^ ((row >> 1) & 3)) << 3)];
    }
#pragma unroll
    for (int ni = 0; ni < 4; ni++) {
      int row = wc * 64 + ni * 16 + lr;
      bf[ni] = *(const s16x8*)&Bs[cur * (128 * 32) + row * 32 + ((lk ^ ((row >> 1) & 3)) << 3)];
    }
#pragma unroll
    for (int mi = 0; mi < 2; mi++)
#pragma unroll
      for (int ni = 0; ni < 4; ni++)
        acc[mi][ni] = __builtin_amdgcn_mfma_f32_16x16x32_bf16(af[mi], bf[ni], acc[mi][ni], 0, 0, 0);
    BARRIER();   // all waves' reads of buf[cur] latched -> safe to re-stage it
    cur ^= 1;
  }
#undef STAGE_
}

// ---- merged Q/K/V projection, 1D grid 1536, XCD-chunked work swizzle ---------
__global__ __launch_bounds__(256)
void gemm_qkv(const unsigned short* __restrict__ qf, const unsigned short* __restrict__ kf,
              const unsigned short* __restrict__ vf,
              const unsigned short* __restrict__ wq, const unsigned short* __restrict__ wk,
              const unsigned short* __restrict__ wv,
              const float* __restrict__ bq, const float* __restrict__ bk,
              const float* __restrict__ bv,
              unsigned short* __restrict__ Qb, unsigned short* __restrict__ Kb,
              unsigned short* __restrict__ Vt,
              const int* __restrict__ cnt) {
  __shared__ __align__(16) unsigned short As[2 * 64 * 32];
  __shared__ __align__(16) unsigned short Bs[2 * 128 * 32];
  // T1: within each z-slice of 512 works, XCD (bid&7) owns 64 contiguous works
  // = 8 A-panels (1 MB) + its weight matrix (2 MB) -> fits 4 MB per-XCD L2
  const int z = blockIdx.x >> 9;
  const int local = blockIdx.x & 511;
  const int wsz = (local & 7) * 64 + (local >> 3);   // bijective (512 = 8*64)
  const int nBase = (wsz & 7) * 128, mBase = (wsz >> 3) * 64;
  const int bb = (mBase >= S_);                      // 64-row tiles never straddle
  if (z) {   // K/V: skip tiles entirely beyond the compacted row count
    if (mBase - bb * S_ >= cnt[bb]) return;
  }
  const unsigned short* A  = (z == 0) ? qf : (z == 1) ? kf : vf;
  const unsigned short* Bw = (z == 0) ? wq : (z == 1) ? wk : wv;
  const float* bias        = (z == 0) ? bq : (z == 1) ? bk : bv;

  const int tid = threadIdx.x, lane = tid & 63;
  const int w = tid >> 6, wr = w >> 1, wc = w & 1;
  const int lr = lane & 15, lk = lane >> 4;

  const f32x4 fz = {0.f, 0.f, 0.f, 0.f};
  f32x4 acc[2][4];
#pragma unroll
  for (int i = 0; i < 2; i++)
#pragma unroll
    for (int j = 0; j < 4; j++) acc[i][j] = fz;

  gemm_core64(A, Bw, As, Bs, mBase, nBase, D_, tid, acc);

  const float alpha = (z == 0) ? 0.125f * LOG2E : 1.0f;   // Q: 1/sqrt(HD) * log2(e)
#pragma unroll
  for (int mi = 0; mi < 2; mi++)
#pragma unroll
    for (int ni = 0; ni < 4; ni++)
#pragma unroll
      for (int r = 0; r < 4; r++) {
        int gr = mBase + wr * 32 + mi * 16 + lk * 4 + r;
        int gc = nBase + wc * 64 + ni * 16 + lr;
        float v = (acc[mi][ni][r] + bias[gc]) * alpha;
        if (z == 2) {        // V^T: [b][h][d][key]
          int s = gr - bb * S_;
          int hI = gc >> 6, dd = gc & 63;
          Vt[((size_t)(bb * H_ + hI) * HD_ + dd) * SKM + s] = f2bf(v);
        } else if (z == 1) { // K rows with per-batch mem-row gap
          int orow = gr + bb * M_;
          Kb[(size_t)orow * D_ + gc] = f2bf(v);
        } else {
          Qb[(size_t)gr * D_ + gc] = f2bf(v);
        }
      }
}

// ---- output projection: f32 out, 1D grid 512, same swizzle -------------------
__global__ __launch_bounds__(256)
void gemm_o(const unsigned short* __restrict__ A, const unsigned short* __restrict__ Bw,
            const float* __restrict__ bias, float* __restrict__ Cout) {
  __shared__ __align__(16) unsigned short As[2 * 64 * 32];
  __shared__ __align__(16) unsigned short Bs[2 * 128 * 32];
  const int local = blockIdx.x & 511;
  const int wsz = (local & 7) * 64 + (local >> 3);
  const int nBase = (wsz & 7) * 128, mBase = (wsz >> 3) * 64;
  const int tid = threadIdx.x, lane = tid & 63;
  const int w = tid >> 6, wr = w >> 1, wc = w & 1;
  const int lr = lane & 15, lk = lane >> 4;

  const f32x4 fz = {0.f, 0.f, 0.f, 0.f};
  f32x4 acc[2][4];
#pragma unroll
  for (int i = 0; i < 2; i++)
#pragma unroll
    for (int j = 0; j < 4; j++) acc[i][j] = fz;

  gemm_core64(A, Bw, As, Bs, mBase, nBase, D_, tid, acc);

#pragma unroll
  for (int mi = 0; mi < 2; mi++)
#pragma unroll
    for (int ni = 0; ni < 4; ni++)
#pragma unroll
      for (int r = 0; r < 4; r++) {
        int gr = mBase + wr * 32 + mi * 16 + lk * 4 + r;
        int gc = nBase + wc * 64 + ni * 16 + lr;
        Cout[(size_t)gr * D_ + gc] = acc[mi][ni][r] + bias[gc];
      }
}

// -------- Flash attention over compacted keys + memory slots ------------------
// Block: 256 q-rows (8 waves x 32) for one (b,h). KV tile = 64 keys.
// Per lane: q = lane&31; P^T in registers; scores in log2 units (LOG2E in Q).
__global__ __launch_bounds__(512)
void attn_kernel(const unsigned short* __restrict__ Qb,
                 const unsigned short* __restrict__ Kb,
                 const unsigned short* __restrict__ VtG,
                 const int* __restrict__ cnt,
                 unsigned short* __restrict__ Xb) {
  __shared__ __align__(16) unsigned short Ks[64 * 64];   // [key][d]  swizzled
  __shared__ __align__(16) unsigned short Vs[64 * 64];   // [d][key]  swizzled

  const int tid = threadIdx.x, lane = tid & 63, w = tid >> 6;   // w: 0..7
  const int l31 = lane & 31, hh = lane >> 5;
  const int qt = blockIdx.x, h = blockIdx.y, b = blockIdx.z;

  const int total = cnt[b] + M_;            // live keys incl. memory slots
  const int nt = (total + 63) >> 6;         // tiles (<= 33)

  const int r0 = tid >> 3, c0 = tid & 7;          // staging: row 0..63, chunk 0..7
  const int ck = c0 ^ (r0 & 7);                   // swizzled chunk
  const unsigned short* Kg = Kb + (size_t)b * SKM * D_ + (size_t)h * HD_;
  const unsigned short* Vg = VtG + (size_t)(b * H_ + h) * HD_ * SKM;

  // Q fragments (B-operand of swapped QK^T): Q[q][ds*16 + hh*8 + i]
  const unsigned short* qp = Qb + ((size_t)(b * S_) + qt * 256 + w * 32 + l31) * D_ + h * HD_;
  s16x8 qf[4];
#pragma unroll
  for (int ds = 0; ds < 4; ds++) qf[ds] = *(const s16x8*)&qp[ds * 16 + hh * 8];

  f32x16 accO[2];
#pragma unroll
  for (int dt = 0; dt < 2; dt++)
#pragma unroll
    for (int j = 0; j < 16; j++) accO[dt][j] = 0.f;
  float m_r = -1e20f, l_r = 0.f;

  uint4 kr0, vr0;
  auto LOAD = [&](int kt) {   // rows < nt*64 <= 2112, always in-bounds
    kr0 = *(const uint4*)&Kg[(size_t)(kt * 64 + r0) * D_ + c0 * 8];
    vr0 = *(const uint4*)&Vg[(size_t)r0 * SKM + kt * 64 + c0 * 8];
  };
  LOAD(0);

  for (int kt = 0; kt < nt; ++kt) {
    __syncthreads();                 // previous tile's LDS reads complete
    *(uint4*)&Ks[r0 * 64 + ck * 8] = kr0;
    *(uint4*)&Vs[r0 * 64 + ck * 8] = vr0;
    __syncthreads();
    if (kt + 1 < nt) LOAD(kt + 1);   // prefetch hides HBM under compute

    // ---- S^T = K · Q^T : p0 = keys 0..31, p1 = keys 32..63 (lane: q=l31) ----
    f32x16 p0, p1;
#pragma unroll
    for (int j = 0; j < 16; j++) { p0[j] = 0.f; p1[j] = 0.f; }
#pragma unroll
    for (int ds = 0; ds < 4; ds++) {
      s16x8 ka0 = *(const s16x8*)&Ks[l31 * 64 + (((ds * 2 + hh) ^ (l31 & 7)) << 3)];
      s16x8 ka1 = *(const s16x8*)&Ks[(32 + l31) * 64 + (((ds * 2 + hh) ^ (l31 & 7)) << 3)];
      p0 = __builtin_amdgcn_mfma_f32_32x32x16_bf16(ka0, qf[ds], p0, 0, 0, 0);
      p1 = __builtin_amdgcn_mfma_f32_32x32x16_bf16(ka1, qf[ds], p1, 0, 0, 0);
    }

    // ---- tail tile: kill keys beyond `total` (key = (j&3)+8*(j>>2)+4*hh) ----
    if (kt == nt - 1) {
      int valid = total - kt * 64;   // 1..64
#pragma unroll
      for (int j = 0; j < 16; j++) {
        int kl = (j & 3) + 8 * (j >> 2) + 4 * hh;
        if (kl >= valid) p0[j] = -1e30f;
        if (kl + 32 >= valid) p1[j] = -1e30f;
      }
    }

    // ---- online softmax in log2 units, defer-max (T13, THR=8) ----
    float vmax = fmaxf(p0[0], p1[0]);
#pragma unroll
    for (int j = 1; j < 16; j++) vmax = fmaxf(vmax, fmaxf(p0[j], p1[j]));
    vmax = fmaxf(vmax, __shfl_xor(vmax, 32));
    if (!__all(vmax - m_r <= 8.0f)) {
      float mnew = fmaxf(m_r, vmax);
      float fac = __builtin_amdgcn_exp2f(m_r - mnew);
      m_r = mnew;
      l_r *= fac;
#pragma unroll
      for (int dt = 0; dt < 2; dt++)
#pragma unroll
        for (int j = 0; j < 16; j++) accO[dt][j] *= fac;
    }
    float sum = 0.f;
#pragma unroll
    for (int j = 0; j < 16; j++) {
      p0[j] = __builtin_amdgcn_exp2f(p0[j] - m_r); sum += p0[j];
      p1[j] = __builtin_amdgcn_exp2f(p1[j] - m_r); sum += p1[j];
    }
    sum += __shfl_xor(sum, 32);
    l_r += sum;

    // ---- build P^T fragments: frag[ks] = P[q][16ks + hh*8 + 0..7] as bf16x8 ----
    s16x8 pf_[4];
#pragma unroll
    for (int ks = 0; ks < 4; ks++) {
      const int base = (ks & 1) * 8;
#define ELT(t) ((ks >= 2) ? p1[base + (t)] : p0[base + (t)])
      unsigned w0 = pkbf(ELT(0), ELT(1));
      unsigned w1 = pkbf(ELT(2), ELT(3));
      unsigned w2 = pkbf(ELT(4), ELT(5));
      unsigned w3 = pkbf(ELT(6), ELT(7));
#undef ELT
      unsigned s0 = hh ? w0 : w2;         // h0 sends keys {8..11}, h1 sends {4..7}
      unsigned s1 = hh ? w1 : w3;
      unsigned g0 = (unsigned)__shfl_xor((int)s0, 32);
      unsigned g1 = (unsigned)__shfl_xor((int)s1, 32);
      union { s16x8 v; unsigned u[4]; } pf;
      pf.u[0] = hh ? g0 : w0;
      pf.u[1] = hh ? g1 : w1;
      pf.u[2] = hh ? w2 : g0;
      pf.u[3] = hh ? w3 : g1;
      pf_[ks] = pf.v;
    }

    // ---- O^T += V^T · P^T  (row d = dt*32+(j&3)+8*(j>>2)+4*hh, col q = l31) ----
#pragma unroll
    for (int dt = 0; dt < 2; dt++)
#pragma unroll
      for (int ks = 0; ks < 4; ks++) {
        s16x8 va = *(const s16x8*)&Vs[(dt * 32 + l31) * 64 + (((ks * 2 + hh) ^ (l31 & 7)) << 3)];
        accO[dt] = __builtin_amdgcn_mfma_f32_32x32x16_bf16(va, pf_[ks], accO[dt], 0, 0, 0);
      }
  }

  float invl = 1.0f / l_r;
  size_t orow = ((size_t)(b * S_) + qt * 256 + w * 32 + l31) * D_ + h * HD_;
#pragma unroll
  for (int dt = 0; dt < 2; dt++)
#pragma unroll
    for (int j = 0; j < 16; j++) {
      int d = dt * 32 + (j & 3) + 8 * (j >> 2) + 4 * hh;
      Xb[orow + d] = f2bf(accO[dt][j] * invl);
    }
}

// ------------------------------- launcher -------------------------------------
extern "C" void kernel_launch(void* const* d_in, const int* in_sizes, int n_in,
                              void* d_out, int out_size, void* d_ws, size_t ws_size,
                              hipStream_t stream) {
  const float* query = (const float*)d_in[0];
  const float* key   = (const float*)d_in[1];
  const float* value = (const float*)d_in[2];
  const int*   mask  = (const int*)d_in[3];
  const float* Wq    = (const float*)d_in[4];
  const float* bq    = (const float*)d_in[5];
  const float* Wk    = (const float*)d_in[6];
  const float* bk    = (const float*)d_in[7];
  const float* Wv    = (const float*)d_in[8];
  const float* bv    = (const float*)d_in[9];
  const float* Wo    = (const float*)d_in[10];
  const float* bo    = (const float*)d_in[11];
  const float* m_k   = (const float*)d_in[12];
  const float* m_v   = (const float*)d_in[13];

  const int NQ = B_ * S_ * D_;     // 4,194,304
  const int NW = D_ * D_;          // 1,048,576 = 2^20
  const int NK = B_ * SKM * D_;    // 4,325,376

  unsigned short* ws = (unsigned short*)d_ws;   // ~67.6 MB + 16 KB
  unsigned short* qf = ws;
  unsigned short* kf = qf + NQ;
  unsigned short* vf = kf + NQ;
  unsigned short* wq = vf + NQ;
  unsigned short* wk = wq + NW;
  unsigned short* wv = wk + NW;
  unsigned short* wo = wv + NW;
  unsigned short* Qb = wo + NW;
  unsigned short* Kb = Qb + NQ;
  unsigned short* Vt = Kb + NK;    // [b][h][d][key]
  unsigned short* Xb = Vt + NK;
  int* idx = (int*)(Xb + NQ);      // [B][S]
  int* cnt = idx + B_ * S_;        // [B]

  compact_mask<<<B_, 256, 0, stream>>>(mask, idx, cnt);
  cvt_kv_gather<<<dim3(S_, B_, 2), 256, 0, stream>>>(key, value, kf, vf, idx, cnt);
  cvt_all<<<(NQ + 4 * NW) / 1024, 256, 0, stream>>>(query, Wq, Wk, Wv, Wo,
                                                    qf, wq, wk, wv, wo);

  // merged Q/K/V projection, 64x128 tiles, 1D grid with XCD-chunked swizzle
  gemm_qkv<<<1536, 256, 0, stream>>>(qf, kf, vf, wq, wk, wv, bq, bk, bv, Qb, Kb, Vt, cnt);
  // memory rows appended at key position cnt[b] — must run AFTER K/V GEMMs
  fill_mem<<<(M_ * D_) / 256, 256, 0, stream>>>(m_k, m_v, Kb, Vt, cnt);

  attn_kernel<<<dim3(S_ / 256, H_, B_), 512, 0, stream>>>(Qb, Kb, Vt, cnt, Xb);

  gemm_o<<<512, 256, 0, stream>>>(Xb, wo, bo, (float*)d_out);
}

// Round 11
// 134.692 us; speedup vs baseline: 1.0583x; 1.0583x over previous
//
#include <hip/hip_runtime.h>
#include <hip/hip_bf16.h>
#include <stdint.h>

// Problem constants (B,S,D,H,M) = (2,2048,1024,16,64), HD=64
#define B_  2
#define S_  2048
#define D_  1024
#define H_  16
#define HD_ 64
#define M_  64
#define SKM (S_ + M_)   // 2112
#define LOG2E 1.44269504088896340736f

typedef __attribute__((ext_vector_type(8))) short s16x8;
typedef __attribute__((ext_vector_type(4))) float f32x4;
typedef __attribute__((ext_vector_type(16))) float f32x16;

// global_load_lds width=16: linear LDS dest (base + lane*16), per-lane global src
#define GLOAD16(gp, lp) __builtin_amdgcn_global_load_lds( \
    (const __attribute__((address_space(1))) void*)(gp),  \
    (__attribute__((address_space(3))) void*)(lp), 16, 0, 0)

// vmcnt wait: literal N, then pin scheduler (rule #18)
#define WAITVM(N) do { asm volatile("s_waitcnt vmcnt(" #N ")" ::: "memory"); \
                       __builtin_amdgcn_sched_barrier(0); } while (0)
// raw s_barrier WITHOUT the __syncthreads vmcnt(0) drain
#define BARRIER() do { asm volatile("" ::: "memory"); \
                       __builtin_amdgcn_s_barrier(); \
                       asm volatile("" ::: "memory"); } while (0)

__device__ __forceinline__ unsigned short f2bf(float f) {
  union { float f; unsigned int u; } v; v.f = f;
  unsigned int r = v.u + 0x7fffu + ((v.u >> 16) & 1u);  // RNE
  return (unsigned short)(r >> 16);
}

__device__ __forceinline__ unsigned pkbf(float lo, float hi) {
  union { __hip_bfloat162 b; unsigned u; } t;
  t.b = __float22bfloat162_rn(make_float2(lo, hi));   // -> v_cvt_pk_bf16_f32
  return t.u;
}

// ---- mask compaction: idx[b][j] = j-th unmasked key, cnt[b] = count ----------
__global__ void compact_mask(const int* __restrict__ mask,
                             int* __restrict__ idx, int* __restrict__ cnt) {
  const int b = blockIdx.x;
  __shared__ int base, wsum[4];
  if (threadIdx.x == 0) base = 0;
  const int lane = threadIdx.x & 63, w = threadIdx.x >> 6;
  __syncthreads();
  for (int c = 0; c < S_; c += 256) {
    int key = c + threadIdx.x;
    int mv = mask[b * S_ + key];
    unsigned long long bal = __ballot(mv != 0);
    int pre = __popcll(bal & ((1ull << lane) - 1ull));
    if (lane == 0) wsum[w] = __popcll(bal);
    __syncthreads();
    int woff = 0;
    for (int i = 0; i < w; i++) woff += wsum[i];
    int tot = wsum[0] + wsum[1] + wsum[2] + wsum[3];
    if (mv) idx[b * S_ + base + woff + pre] = key;
    __syncthreads();
    if (threadIdx.x == 0) base += tot;
    __syncthreads();
  }
  if (threadIdx.x == 0) cnt[b] = base;
}

// ---- ALL conversions in ONE launch: query + 4 weights + K/V gather -----------
// bid < 8192: linear cvt of [query | Wq | Wk | Wv | Wo] (4 elems/thread)
// bid >= 8192: gather-convert one key/value row through idx (mask=1 rows only)
__global__ void cvt_fused(const float* __restrict__ q,
                          const float* __restrict__ w0, const float* __restrict__ w1,
                          const float* __restrict__ w2, const float* __restrict__ w3,
                          const float* __restrict__ key, const float* __restrict__ value,
                          unsigned short* __restrict__ qf,
                          unsigned short* __restrict__ o0, unsigned short* __restrict__ o1,
                          unsigned short* __restrict__ o2, unsigned short* __restrict__ o3,
                          unsigned short* __restrict__ kf, unsigned short* __restrict__ vf,
                          const int* __restrict__ idx, const int* __restrict__ cnt) {
  const size_t NQs = (size_t)B_ * S_ * D_;
  if (blockIdx.x < 8192) {
    size_t i = ((size_t)blockIdx.x * 256 + threadIdx.x) * 4;
    const float* in; unsigned short* out; size_t off;
    if (i < NQs) { in = q; out = qf; off = i; }
    else {
      size_t j = i - NQs;
      int wsel = (int)(j >> 20);
      off = j & ((1u << 20) - 1);
      in  = (wsel == 0) ? w0 : (wsel == 1) ? w1 : (wsel == 2) ? w2 : w3;
      out = (wsel == 0) ? o0 : (wsel == 1) ? o1 : (wsel == 2) ? o2 : o3;
    }
    float4 v = *(const float4*)&in[off];
    ushort4 o;
    o.x = f2bf(v.x); o.y = f2bf(v.y); o.z = f2bf(v.z); o.w = f2bf(v.w);
    *(ushort4*)&out[off] = o;
  } else {
    int gid = blockIdx.x - 8192;         // [0, 8192)
    int kv = gid >> 12, rem = gid & 4095;
    int b = rem >> 11, j = rem & 2047;
    if (j >= cnt[b]) return;
    const float* in = kv ? value : key;
    unsigned short* out = kv ? vf : kf;
    int src = idx[b * S_ + j];
    const float* ip = in + ((size_t)(b * S_) + src) * D_;
    unsigned short* op = out + ((size_t)(b * S_) + j) * D_;
    int t = threadIdx.x * 4;
    float4 v = *(const float4*)&ip[t];
    ushort4 o;
    o.x = f2bf(v.x); o.y = f2bf(v.y); o.z = f2bf(v.z); o.w = f2bf(v.w);
    *(ushort4*)&op[t] = o;
  }
}

// ---- memory rows appended at key position cnt[b] (AFTER the K/V GEMMs) -------
__global__ void fill_mem(const float* __restrict__ mk, const float* __restrict__ mv,
                         unsigned short* __restrict__ Kb, unsigned short* __restrict__ VtG,
                         const int* __restrict__ cnt) {
  int i = blockIdx.x * 256 + threadIdx.x;     // 0 .. M_*D_-1
  int row = i >> 10, col = i & 1023;
  int hI = col >> 6, dd = col & 63;
  unsigned short kv = f2bf(8.0f * mk[i]);
  unsigned short vv = f2bf(8.0f * mv[i]);
#pragma unroll
  for (int b = 0; b < B_; b++) {
    int c = cnt[b];
    Kb[((size_t)(b * SKM) + c + row) * D_ + col] = kv;
    VtG[((size_t)(b * H_ + hI) * HD_ + dd) * SKM + c + row] = vv;
  }
}

// ------ GEMM core: 128x128 tile, BK=32, 2-buffer, SINGLE barrier per K-step ---
// Minimum 2-phase template (catalog T3-minimum, m228d/m248v2 verified class):
//   STAGE(next) -> ds_read(cur)+MFMA -> vmcnt(0)+barrier.
// The vmcnt(0) drain lands a full compute phase after issue. One barrier per
// tile suffices: a wave passing it has already register-latched its reads
// (compiler lgkmcnt before MFMA), so re-staging that buffer next step is safe.
// Swizzle invariant (rule #21): LDS[r][c] = global[r][c ^ ((r>>1)&3)].
__device__ __forceinline__ void gemm_core2(
    const unsigned short* __restrict__ A,
    const unsigned short* __restrict__ Bw,
    unsigned short* As, unsigned short* Bs,   // each 2*128*32 elems
    int mBase, int nBase, int K,
    int w, int lane, int wr, int wc, int lr, int lk,
    f32x4 acc[4][4]) {
  const int srow = w * 32 + (lane >> 2);    // staging rows: srow, srow+16
  const int cd = lane & 3;                  // dest chunk (linear)
  const int NT = K / 32;

#define STAGE_(buf, k0)                                                          \
  {                                                                              \
    _Pragma("unroll")                                                            \
    for (int i = 0; i < 2; i++) {                                                \
      int r = srow + i * 16;                                                     \
      int ca = cd ^ ((r >> 1) & 3);       /* inverse-swizzled source chunk */    \
      GLOAD16(&A[(size_t)(mBase + r) * K + (k0) + ca * 8],                       \
              &As[(buf) * (128 * 32) + (w * 32 + i * 16) * 32]);                 \
      GLOAD16(&Bw[(size_t)(nBase + r) * K + (k0) + ca * 8],                      \
              &Bs[(buf) * (128 * 32) + (w * 32 + i * 16) * 32]);                 \
    }                                                                            \
  }

  STAGE_(0, 0);
  WAITVM(0);
  BARRIER();                                 // buf0 staged for all waves
  int cur = 0;
  for (int t = 0; t < NT; ++t) {
    if (t + 1 < NT) STAGE_(cur ^ 1, (t + 1) * 32);   // issue BEFORE compute
    s16x8 af[4], bf[4];
#pragma unroll
    for (int mi = 0; mi < 4; mi++) {
      int row = wr * 64 + mi * 16 + lr;
      af[mi] = *(const s16x8*)&As[cur * (128 * 32) + row * 32 + ((lk ^ ((row >> 1) & 3)) << 3)];
    }
#pragma unroll
    for (int ni = 0; ni < 4; ni++) {
      int row = wc * 64 + ni * 16 + lr;
      bf[ni] = *(const s16x8*)&Bs[cur * (128 * 32) + row * 32 + ((lk ^ ((row >> 1) & 3)) << 3)];
    }
    __builtin_amdgcn_s_setprio(1);
#pragma unroll
    for (int mi = 0; mi < 4; mi++)
#pragma unroll
      for (int ni = 0; ni < 4; ni++)
        acc[mi][ni] = __builtin_amdgcn_mfma_f32_16x16x32_bf16(af[mi], bf[ni], acc[mi][ni], 0, 0, 0);
    __builtin_amdgcn_s_setprio(0);
    WAITVM(0);   // drains next tile's DMA (issued a full compute phase ago)
    BARRIER();   // all waves: reads latched + next tile staged
    cur ^= 1;
  }
#undef STAGE_
}

// ---- merged Q/K/V projection, 1D grid 768, XCD-chunked work swizzle ----------
__global__ __launch_bounds__(256)
void gemm_qkv(const unsigned short* __restrict__ qf, const unsigned short* __restrict__ kf,
              const unsigned short* __restrict__ vf,
              const unsigned short* __restrict__ wq, const unsigned short* __restrict__ wk,
              const unsigned short* __restrict__ wv,
              const float* __restrict__ bq, const float* __restrict__ bk,
              const float* __restrict__ bv,
              unsigned short* __restrict__ Qb, unsigned short* __restrict__ Kb,
              unsigned short* __restrict__ Vt,
              const int* __restrict__ cnt) {
  __shared__ __align__(16) unsigned short As[2 * 128 * 32];
  __shared__ __align__(16) unsigned short Bs[2 * 128 * 32];
  // T1: within each z-slice of 256 works, XCD (bid&7) owns 32 contiguous works
  const int z = blockIdx.x >> 8;
  const int local = blockIdx.x & 255;
  const int wsz = (local & 7) * 32 + (local >> 3);   // bijective (256 = 8*32)
  const int nBase = (wsz & 7) * 128, mBase = (wsz >> 3) * 128;
  const int bb = (mBase >= S_);
  if (z) {   // K/V: skip tiles entirely beyond the compacted row count
    if (mBase - bb * S_ >= cnt[bb]) return;
  }
  const unsigned short* A  = (z == 0) ? qf : (z == 1) ? kf : vf;
  const unsigned short* Bw = (z == 0) ? wq : (z == 1) ? wk : wv;
  const float* bias        = (z == 0) ? bq : (z == 1) ? bk : bv;

  const int tid = threadIdx.x, lane = tid & 63;
  const int w = tid >> 6, wr = w >> 1, wc = w & 1;
  const int lr = lane & 15, lk = lane >> 4;

  const f32x4 fz = {0.f, 0.f, 0.f, 0.f};
  f32x4 acc[4][4];
#pragma unroll
  for (int i = 0; i < 4; i++)
#pragma unroll
    for (int j = 0; j < 4; j++) acc[i][j] = fz;

  gemm_core2(A, Bw, As, Bs, mBase, nBase, D_, w, lane, wr, wc, lr, lk, acc);

  const float alpha = (z == 0) ? 0.125f * LOG2E : 1.0f;   // Q: 1/sqrt(HD) * log2(e)
#pragma unroll
  for (int mi = 0; mi < 4; mi++)
#pragma unroll
    for (int ni = 0; ni < 4; ni++)
#pragma unroll
      for (int r = 0; r < 4; r++) {
        int gr = mBase + wr * 64 + mi * 16 + lk * 4 + r;
        int gc = nBase + wc * 64 + ni * 16 + lr;
        float v = (acc[mi][ni][r] + bias[gc]) * alpha;
        if (z == 2) {        // V^T: [b][h][d][key]
          int s = gr - bb * S_;
          int hI = gc >> 6, dd = gc & 63;
          Vt[((size_t)(bb * H_ + hI) * HD_ + dd) * SKM + s] = f2bf(v);
        } else if (z == 1) { // K rows with per-batch mem-row gap
          int orow = gr + bb * M_;
          Kb[(size_t)orow * D_ + gc] = f2bf(v);
        } else {
          Qb[(size_t)gr * D_ + gc] = f2bf(v);
        }
      }
}

// ---- output projection: f32 out, 1D grid 256, same swizzle -------------------
__global__ __launch_bounds__(256)
void gemm_o(const unsigned short* __restrict__ A, const unsigned short* __restrict__ Bw,
            const float* __restrict__ bias, float* __restrict__ Cout) {
  __shared__ __align__(16) unsigned short As[2 * 128 * 32];
  __shared__ __align__(16) unsigned short Bs[2 * 128 * 32];
  const int local = blockIdx.x & 255;
  const int wsz = (local & 7) * 32 + (local >> 3);
  const int nBase = (wsz & 7) * 128, mBase = (wsz >> 3) * 128;
  const int tid = threadIdx.x, lane = tid & 63;
  const int w = tid >> 6, wr = w >> 1, wc = w & 1;
  const int lr = lane & 15, lk = lane >> 4;

  const f32x4 fz = {0.f, 0.f, 0.f, 0.f};
  f32x4 acc[4][4];
#pragma unroll
  for (int i = 0; i < 4; i++)
#pragma unroll
    for (int j = 0; j < 4; j++) acc[i][j] = fz;

  gemm_core2(A, Bw, As, Bs, mBase, nBase, D_, w, lane, wr, wc, lr, lk, acc);

#pragma unroll
  for (int mi = 0; mi < 4; mi++)
#pragma unroll
    for (int ni = 0; ni < 4; ni++)
#pragma unroll
      for (int r = 0; r < 4; r++) {
        int gr = mBase + wr * 64 + mi * 16 + lk * 4 + r;
        int gc = nBase + wc * 64 + ni * 16 + lr;
        Cout[(size_t)gr * D_ + gc] = acc[mi][ni][r] + bias[gc];
      }
}

// -------- Flash attention over compacted keys + memory slots ------------------
// Block: 256 q-rows (8 waves x 32) for one (b,h). KV tile = 64 keys.
// Per lane: q = lane&31; P^T in registers; scores in log2 units (LOG2E in Q).
__global__ __launch_bounds__(512)
void attn_kernel(const unsigned short* __restrict__ Qb,
                 const unsigned short* __restrict__ Kb,
                 const unsigned short* __restrict__ VtG,
                 const int* __restrict__ cnt,
                 unsigned short* __restrict__ Xb) {
  __shared__ __align__(16) unsigned short Ks[64 * 64];   // [key][d]  swizzled
  __shared__ __align__(16) unsigned short Vs[64 * 64];   // [d][key]  swizzled

  const int tid = threadIdx.x, lane = tid & 63, w = tid >> 6;   // w: 0..7
  const int l31 = lane & 31, hh = lane >> 5;
  const int qt = blockIdx.x, h = blockIdx.y, b = blockIdx.z;

  const int total = cnt[b] + M_;            // live keys incl. memory slots
  const int nt = (total + 63) >> 6;         // tiles (<= 33)

  const int r0 = tid >> 3, c0 = tid & 7;          // staging: row 0..63, chunk 0..7
  const int ck = c0 ^ (r0 & 7);                   // swizzled chunk
  const unsigned short* Kg = Kb + (size_t)b * SKM * D_ + (size_t)h * HD_;
  const unsigned short* Vg = VtG + (size_t)(b * H_ + h) * HD_ * SKM;

  // Q fragments (B-operand of swapped QK^T): Q[q][ds*16 + hh*8 + i]
  const unsigned short* qp = Qb + ((size_t)(b * S_) + qt * 256 + w * 32 + l31) * D_ + h * HD_;
  s16x8 qf[4];
#pragma unroll
  for (int ds = 0; ds < 4; ds++) qf[ds] = *(const s16x8*)&qp[ds * 16 + hh * 8];

  f32x16 accO[2];
#pragma unroll
  for (int dt = 0; dt < 2; dt++)
#pragma unroll
    for (int j = 0; j < 16; j++) accO[dt][j] = 0.f;
  float m_r = -1e20f, l_r = 0.f;

  uint4 kr0, vr0;
  auto LOAD = [&](int kt) {   // rows < nt*64 <= 2112, always in-bounds
    kr0 = *(const uint4*)&Kg[(size_t)(kt * 64 + r0) * D_ + c0 * 8];
    vr0 = *(const uint4*)&Vg[(size_t)r0 * SKM + kt * 64 + c0 * 8];
  };
  LOAD(0);

  for (int kt = 0; kt < nt; ++kt) {
    __syncthreads();                 // previous tile's LDS reads complete
    *(uint4*)&Ks[r0 * 64 + ck * 8] = kr0;
    *(uint4*)&Vs[r0 * 64 + ck * 8] = vr0;
    __syncthreads();
    if (kt + 1 < nt) LOAD(kt + 1);   // prefetch hides HBM under compute

    // ---- S^T = K · Q^T : p0 = keys 0..31, p1 = keys 32..63 (lane: q=l31) ----
    f32x16 p0, p1;
#pragma unroll
    for (int j = 0; j < 16; j++) { p0[j] = 0.f; p1[j] = 0.f; }
    __builtin_amdgcn_s_setprio(1);
#pragma unroll
    for (int ds = 0; ds < 4; ds++) {
      s16x8 ka0 = *(const s16x8*)&Ks[l31 * 64 + (((ds * 2 + hh) ^ (l31 & 7)) << 3)];
      s16x8 ka1 = *(const s16x8*)&Ks[(32 + l31) * 64 + (((ds * 2 + hh) ^ (l31 & 7)) << 3)];
      p0 = __builtin_amdgcn_mfma_f32_32x32x16_bf16(ka0, qf[ds], p0, 0, 0, 0);
      p1 = __builtin_amdgcn_mfma_f32_32x32x16_bf16(ka1, qf[ds], p1, 0, 0, 0);
    }
    __builtin_amdgcn_s_setprio(0);

    // ---- tail tile: kill keys beyond `total` (key = (j&3)+8*(j>>2)+4*hh) ----
    if (kt == nt - 1) {
      int valid = total - kt * 64;   // 1..64
#pragma unroll
      for (int j = 0; j < 16; j++) {
        int kl = (j & 3) + 8 * (j >> 2) + 4 * hh;
        if (kl >= valid) p0[j] = -1e30f;
        if (kl + 32 >= valid) p1[j] = -1e30f;
      }
    }

    // ---- online softmax in log2 units, defer-max (T13, THR=8) ----
    float vmax = fmaxf(p0[0], p1[0]);
#pragma unroll
    for (int j = 1; j < 16; j++) vmax = fmaxf(vmax, fmaxf(p0[j], p1[j]));
    vmax = fmaxf(vmax, __shfl_xor(vmax, 32));
    if (!__all(vmax - m_r <= 8.0f)) {
      float mnew = fmaxf(m_r, vmax);
      float fac = __builtin_amdgcn_exp2f(m_r - mnew);
      m_r = mnew;
      l_r *= fac;
#pragma unroll
      for (int dt = 0; dt < 2; dt++)
#pragma unroll
        for (int j = 0; j < 16; j++) accO[dt][j] *= fac;
    }
    float sum = 0.f;
#pragma unroll
    for (int j = 0; j < 16; j++) {
      p0[j] = __builtin_amdgcn_exp2f(p0[j] - m_r); sum += p0[j];
      p1[j] = __builtin_amdgcn_exp2f(p1[j] - m_r); sum += p1[j];
    }
    sum += __shfl_xor(sum, 32);
    l_r += sum;

    // ---- build P^T fragments: frag[ks] = P[q][16ks + hh*8 + 0..7] as bf16x8 ----
    s16x8 pf_[4];
#pragma unroll
    for (int ks = 0; ks < 4; ks++) {
      const int base = (ks & 1) * 8;
#define ELT(t) ((ks >= 2) ? p1[base + (t)] : p0[base + (t)])
      unsigned w0 = pkbf(ELT(0), ELT(1));
      unsigned w1 = pkbf(ELT(2), ELT(3));
      unsigned w2 = pkbf(ELT(4), ELT(5));
      unsigned w3 = pkbf(ELT(6), ELT(7));
#undef ELT
      unsigned s0 = hh ? w0 : w2;         // h0 sends keys {8..11}, h1 sends {4..7}
      unsigned s1 = hh ? w1 : w3;
      unsigned g0 = (unsigned)__shfl_xor((int)s0, 32);
      unsigned g1 = (unsigned)__shfl_xor((int)s1, 32);
      union { s16x8 v; unsigned u[4]; } pf;
      pf.u[0] = hh ? g0 : w0;
      pf.u[1] = hh ? g1 : w1;
      pf.u[2] = hh ? w2 : g0;
      pf.u[3] = hh ? w3 : g1;
      pf_[ks] = pf.v;
    }

    // ---- O^T += V^T · P^T  (row d = dt*32+(j&3)+8*(j>>2)+4*hh, col q = l31) ----
    __builtin_amdgcn_s_setprio(1);
#pragma unroll
    for (int dt = 0; dt < 2; dt++)
#pragma unroll
      for (int ks = 0; ks < 4; ks++) {
        s16x8 va = *(const s16x8*)&Vs[(dt * 32 + l31) * 64 + (((ks * 2 + hh) ^ (l31 & 7)) << 3)];
        accO[dt] = __builtin_amdgcn_mfma_f32_32x32x16_bf16(va, pf_[ks], accO[dt], 0, 0, 0);
      }
    __builtin_amdgcn_s_setprio(0);
  }

  float invl = 1.0f / l_r;
  size_t orow = ((size_t)(b * S_) + qt * 256 + w * 32 + l31) * D_ + h * HD_;
#pragma unroll
  for (int dt = 0; dt < 2; dt++)
#pragma unroll
    for (int j = 0; j < 16; j++) {
      int d = dt * 32 + (j & 3) + 8 * (j >> 2) + 4 * hh;
      Xb[orow + d] = f2bf(accO[dt][j] * invl);
    }
}

// ------------------------------- launcher -------------------------------------
extern "C" void kernel_launch(void* const* d_in, const int* in_sizes, int n_in,
                              void* d_out, int out_size, void* d_ws, size_t ws_size,
                              hipStream_t stream) {
  const float* query = (const float*)d_in[0];
  const float* key   = (const float*)d_in[1];
  const float* value = (const float*)d_in[2];
  const int*   mask  = (const int*)d_in[3];
  const float* Wq    = (const float*)d_in[4];
  const float* bq    = (const float*)d_in[5];
  const float* Wk    = (const float*)d_in[6];
  const float* bk    = (const float*)d_in[7];
  const float* Wv    = (const float*)d_in[8];
  const float* bv    = (const float*)d_in[9];
  const float* Wo    = (const float*)d_in[10];
  const float* bo    = (const float*)d_in[11];
  const float* m_k   = (const float*)d_in[12];
  const float* m_v   = (const float*)d_in[13];

  const int NQ = B_ * S_ * D_;     // 4,194,304
  const int NW = D_ * D_;          // 1,048,576 = 2^20
  const int NK = B_ * SKM * D_;    // 4,325,376

  unsigned short* ws = (unsigned short*)d_ws;   // ~67.6 MB + 16 KB
  unsigned short* qf = ws;
  unsigned short* kf = qf + NQ;
  unsigned short* vf = kf + NQ;
  unsigned short* wq = vf + NQ;
  unsigned short* wk = wq + NW;
  unsigned short* wv = wk + NW;
  unsigned short* wo = wv + NW;
  unsigned short* Qb = wo + NW;
  unsigned short* Kb = Qb + NQ;
  unsigned short* Vt = Kb + NK;    // [b][h][d][key]
  unsigned short* Xb = Vt + NK;
  int* idx = (int*)(Xb + NQ);      // [B][S]
  int* cnt = idx + B_ * S_;        // [B]

  compact_mask<<<B_, 256, 0, stream>>>(mask, idx, cnt);
  // one launch: query+weights linear cvt (8192 blocks) + K/V gather (8192)
  cvt_fused<<<16384, 256, 0, stream>>>(query, Wq, Wk, Wv, Wo, key, value,
                                       qf, wq, wk, wv, wo, kf, vf, idx, cnt);

  // merged Q/K/V projection, 128x128 tiles, single-barrier 2-phase core
  gemm_qkv<<<768, 256, 0, stream>>>(qf, kf, vf, wq, wk, wv, bq, bk, bv, Qb, Kb, Vt, cnt);
  // memory rows appended at key position cnt[b] — must run AFTER K/V GEMMs
  fill_mem<<<(M_ * D_) / 256, 256, 0, stream>>>(m_k, m_v, Kb, Vt, cnt);

  attn_kernel<<<dim3(S_ / 256, H_, B_), 512, 0, stream>>>(Qb, Kb, Vt, cnt, Xb);

  gemm_o<<<256, 256, 0, stream>>>(Xb, wo, bo, (float*)d_out);
}

// Round 12
// 124.970 us; speedup vs baseline: 1.1407x; 1.0778x over previous
//
#include <hip/hip_runtime.h>
#include <hip/hip_bf16.h>
#include <stdint.h>

// Problem constants (B,S,D,H,M) = (2,2048,1024,16,64), HD=64
#define B_  2
#define S_  2048
#define D_  1024
#define H_  16
#define HD_ 64
#define M_  64
#define SKM (S_ + M_)   // 2112
#define LOG2E 1.44269504088896340736f

typedef __attribute__((ext_vector_type(8))) short s16x8;
typedef __attribute__((ext_vector_type(4))) float f32x4;
typedef __attribute__((ext_vector_type(16))) float f32x16;

// global_load_lds width=16: linear LDS dest (base + lane*16), per-lane global src
#define GLOAD16(gp, lp) __builtin_amdgcn_global_load_lds( \
    (const __attribute__((address_space(1))) void*)(gp),  \
    (__attribute__((address_space(3))) void*)(lp), 16, 0, 0)

// counted vmcnt wait (T4): literal N, then pin scheduler (rule #18)
#define WAITVM(N) do { asm volatile("s_waitcnt vmcnt(" #N ")" ::: "memory"); \
                       __builtin_amdgcn_sched_barrier(0); } while (0)
// raw s_barrier WITHOUT the __syncthreads vmcnt(0) drain
#define BARRIER() do { asm volatile("" ::: "memory"); \
                       __builtin_amdgcn_s_barrier(); \
                       asm volatile("" ::: "memory"); } while (0)

__device__ __forceinline__ unsigned short f2bf(float f) {
  union { float f; unsigned int u; } v; v.f = f;
  unsigned int r = v.u + 0x7fffu + ((v.u >> 16) & 1u);  // RNE
  return (unsigned short)(r >> 16);
}

__device__ __forceinline__ unsigned pkbf(float lo, float hi) {
  union { __hip_bfloat162 b; unsigned u; } t;
  t.b = __float22bfloat162_rn(make_float2(lo, hi));   // -> v_cvt_pk_bf16_f32
  return t.u;
}

// ---- mask compaction: idx[b][j] = j-th unmasked key, cnt[b] = count ----------
__global__ void compact_mask(const int* __restrict__ mask,
                             int* __restrict__ idx, int* __restrict__ cnt) {
  const int b = blockIdx.x;
  __shared__ int base, wsum[4];
  if (threadIdx.x == 0) base = 0;
  const int lane = threadIdx.x & 63, w = threadIdx.x >> 6;
  __syncthreads();
  for (int c = 0; c < S_; c += 256) {
    int key = c + threadIdx.x;
    int mv = mask[b * S_ + key];
    unsigned long long bal = __ballot(mv != 0);
    int pre = __popcll(bal & ((1ull << lane) - 1ull));
    if (lane == 0) wsum[w] = __popcll(bal);
    __syncthreads();
    int woff = 0;
    for (int i = 0; i < w; i++) woff += wsum[i];
    int tot = wsum[0] + wsum[1] + wsum[2] + wsum[3];
    if (mv) idx[b * S_ + base + woff + pre] = key;
    __syncthreads();
    if (threadIdx.x == 0) base += tot;
    __syncthreads();
  }
  if (threadIdx.x == 0) cnt[b] = base;
}

// ---- ALL conversions in ONE launch: query + 4 weights + K/V gather -----------
// bid < 8192: linear cvt of [query | Wq | Wk | Wv | Wo] (4 elems/thread)
// bid >= 8192: gather-convert one key/value row through idx (mask=1 rows only)
__global__ void cvt_fused(const float* __restrict__ q,
                          const float* __restrict__ w0, const float* __restrict__ w1,
                          const float* __restrict__ w2, const float* __restrict__ w3,
                          const float* __restrict__ key, const float* __restrict__ value,
                          unsigned short* __restrict__ qf,
                          unsigned short* __restrict__ o0, unsigned short* __restrict__ o1,
                          unsigned short* __restrict__ o2, unsigned short* __restrict__ o3,
                          unsigned short* __restrict__ kf, unsigned short* __restrict__ vf,
                          const int* __restrict__ idx, const int* __restrict__ cnt) {
  const size_t NQs = (size_t)B_ * S_ * D_;
  if (blockIdx.x < 8192) {
    size_t i = ((size_t)blockIdx.x * 256 + threadIdx.x) * 4;
    const float* in; unsigned short* out; size_t off;
    if (i < NQs) { in = q; out = qf; off = i; }
    else {
      size_t j = i - NQs;
      int wsel = (int)(j >> 20);
      off = j & ((1u << 20) - 1);
      in  = (wsel == 0) ? w0 : (wsel == 1) ? w1 : (wsel == 2) ? w2 : w3;
      out = (wsel == 0) ? o0 : (wsel == 1) ? o1 : (wsel == 2) ? o2 : o3;
    }
    float4 v = *(const float4*)&in[off];
    ushort4 o;
    o.x = f2bf(v.x); o.y = f2bf(v.y); o.z = f2bf(v.z); o.w = f2bf(v.w);
    *(ushort4*)&out[off] = o;
  } else {
    int gid = blockIdx.x - 8192;         // [0, 8192)
    int kv = gid >> 12, rem = gid & 4095;
    int b = rem >> 11, j = rem & 2047;
    if (j >= cnt[b]) return;
    const float* in = kv ? value : key;
    unsigned short* out = kv ? vf : kf;
    int src = idx[b * S_ + j];
    const float* ip = in + ((size_t)(b * S_) + src) * D_;
    unsigned short* op = out + ((size_t)(b * S_) + j) * D_;
    int t = threadIdx.x * 4;
    float4 v = *(const float4*)&ip[t];
    ushort4 o;
    o.x = f2bf(v.x); o.y = f2bf(v.y); o.z = f2bf(v.z); o.w = f2bf(v.w);
    *(ushort4*)&op[t] = o;
  }
}

// ---- memory rows appended at key position cnt[b] (AFTER the K/V GEMMs) -------
__global__ void fill_mem(const float* __restrict__ mk, const float* __restrict__ mv,
                         unsigned short* __restrict__ Kb, unsigned short* __restrict__ VtG,
                         const int* __restrict__ cnt) {
  int i = blockIdx.x * 256 + threadIdx.x;     // 0 .. M_*D_-1
  int row = i >> 10, col = i & 1023;
  int hI = col >> 6, dd = col & 63;
  unsigned short kv = f2bf(8.0f * mk[i]);
  unsigned short vv = f2bf(8.0f * mv[i]);
#pragma unroll
  for (int b = 0; b < B_; b++) {
    int c = cnt[b];
    Kb[((size_t)(b * SKM) + c + row) * D_ + col] = kv;
    VtG[((size_t)(b * H_ + hI) * HD_ + dd) * SKM + c + row] = vv;
  }
}

// ------ GEMM core: 128x128 tile, BK=32, 8 waves (64x32/wave), 2-buffer --------
// R7-proven schedule (two barriers + counted vmcnt, never 0 in main loop), but
// 8 waves per block: doubles waves/SIMD at identical LDS/grid/traffic — the
// latency hiding comes from wave TLP instead of pipeline depth (R8) or block
// count (R10). Staging: 1 A-load + 1 B-load per thread -> WAITVM(2) steady.
// Swizzle invariant (rule #21): LDS[r][c] = global[r][c ^ ((r>>1)&3)].
__device__ __forceinline__ void gemm_core2(
    const unsigned short* __restrict__ A,
    const unsigned short* __restrict__ Bw,
    unsigned short* As, unsigned short* Bs,   // each 2*128*32 elems
    int mBase, int nBase, int K,
    int tid, f32x4 acc[4][2]) {
  const int lane = tid & 63, w = tid >> 6;          // w: 0..7
  const int wr = w >> 2, wc = w & 3;                // wave grid 2x4 (64x32 each)
  const int lr = lane & 15, lk = lane >> 4;
  const int srow = tid >> 2;                        // staging row 0..127
  const int cd = tid & 3;                           // dest chunk (linear)
  const int ca = cd ^ ((srow >> 1) & 3);            // inverse-swizzled src chunk
  const int NT = K / 32;

#define STAGE_(buf, k0)                                                          \
  {                                                                              \
    GLOAD16(&A[(size_t)(mBase + srow) * K + (k0) + ca * 8],                      \
            &As[(buf) * (128 * 32) + (w * 16) * 32]);                            \
    GLOAD16(&Bw[(size_t)(nBase + srow) * K + (k0) + ca * 8],                     \
            &Bs[(buf) * (128 * 32) + (w * 16) * 32]);                            \
  }

  STAGE_(0, 0);                              // 2 loads in flight
  int cur = 0;
  for (int t = 0; t < NT; ++t) {
    if (t + 1 < NT) {
      STAGE_(cur ^ 1, (t + 1) * 32);         // 4 in flight
      WAITVM(2);                             // tile t's 2 done; t+1's in flight
    } else {
      WAITVM(0);
    }
    BARRIER();                               // all waves: tile t staged
    s16x8 af[4], bf[2];
#pragma unroll
    for (int mi = 0; mi < 4; mi++) {
      int row = wr * 64 + mi * 16 + lr;
      af[mi] = *(const s16x8*)&As[cur * (128 * 32) + row * 32 + ((lk ^ ((row >> 1) & 3)) << 3)];
    }
#pragma unroll
    for (int ni = 0; ni < 2; ni++) {
      int row = wc * 32 + ni * 16 + lr;
      bf[ni] = *(const s16x8*)&Bs[cur * (128 * 32) + row * 32 + ((lk ^ ((row >> 1) & 3)) << 3)];
    }
#pragma unroll
    for (int mi = 0; mi < 4; mi++)
#pragma unroll
      for (int ni = 0; ni < 2; ni++)
        acc[mi][ni] = __builtin_amdgcn_mfma_f32_16x16x32_bf16(af[mi], bf[ni], acc[mi][ni], 0, 0, 0);
    BARRIER();   // all waves' reads of buf[cur] latched -> safe to re-stage it
    cur ^= 1;
  }
#undef STAGE_
}

// ---- merged Q/K/V projection, 1D grid 768, XCD-chunked work swizzle ----------
__global__ __launch_bounds__(512)
void gemm_qkv(const unsigned short* __restrict__ qf, const unsigned short* __restrict__ kf,
              const unsigned short* __restrict__ vf,
              const unsigned short* __restrict__ wq, const unsigned short* __restrict__ wk,
              const unsigned short* __restrict__ wv,
              const float* __restrict__ bq, const float* __restrict__ bk,
              const float* __restrict__ bv,
              unsigned short* __restrict__ Qb, unsigned short* __restrict__ Kb,
              unsigned short* __restrict__ Vt,
              const int* __restrict__ cnt) {
  __shared__ __align__(16) unsigned short As[2 * 128 * 32];
  __shared__ __align__(16) unsigned short Bs[2 * 128 * 32];
  // T1: within each z-slice of 256 works, XCD (bid&7) owns 32 contiguous works
  const int z = blockIdx.x >> 8;
  const int local = blockIdx.x & 255;
  const int wsz = (local & 7) * 32 + (local >> 3);   // bijective (256 = 8*32)
  const int nBase = (wsz & 7) * 128, mBase = (wsz >> 3) * 128;
  const int bb = (mBase >= S_);
  if (z) {   // K/V: skip tiles entirely beyond the compacted row count
    if (mBase - bb * S_ >= cnt[bb]) return;
  }
  const unsigned short* A  = (z == 0) ? qf : (z == 1) ? kf : vf;
  const unsigned short* Bw = (z == 0) ? wq : (z == 1) ? wk : wv;
  const float* bias        = (z == 0) ? bq : (z == 1) ? bk : bv;

  const int tid = threadIdx.x, lane = tid & 63;
  const int w = tid >> 6, wr = w >> 2, wc = w & 3;
  const int lr = lane & 15, lk = lane >> 4;

  const f32x4 fz = {0.f, 0.f, 0.f, 0.f};
  f32x4 acc[4][2];
#pragma unroll
  for (int i = 0; i < 4; i++)
#pragma unroll
    for (int j = 0; j < 2; j++) acc[i][j] = fz;

  gemm_core2(A, Bw, As, Bs, mBase, nBase, D_, tid, acc);

  const float alpha = (z == 0) ? 0.125f * LOG2E : 1.0f;   // Q: 1/sqrt(HD) * log2(e)
#pragma unroll
  for (int mi = 0; mi < 4; mi++)
#pragma unroll
    for (int ni = 0; ni < 2; ni++)
#pragma unroll
      for (int r = 0; r < 4; r++) {
        int gr = mBase + wr * 64 + mi * 16 + lk * 4 + r;
        int gc = nBase + wc * 32 + ni * 16 + lr;
        float v = (acc[mi][ni][r] + bias[gc]) * alpha;
        if (z == 2) {        // V^T: [b][h][d][key]
          int s = gr - bb * S_;
          int hI = gc >> 6, dd = gc & 63;
          Vt[((size_t)(bb * H_ + hI) * HD_ + dd) * SKM + s] = f2bf(v);
        } else if (z == 1) { // K rows with per-batch mem-row gap
          int orow = gr + bb * M_;
          Kb[(size_t)orow * D_ + gc] = f2bf(v);
        } else {
          Qb[(size_t)gr * D_ + gc] = f2bf(v);
        }
      }
}

// ---- output projection: f32 out, 1D grid 256, same swizzle -------------------
__global__ __launch_bounds__(512)
void gemm_o(const unsigned short* __restrict__ A, const unsigned short* __restrict__ Bw,
            const float* __restrict__ bias, float* __restrict__ Cout) {
  __shared__ __align__(16) unsigned short As[2 * 128 * 32];
  __shared__ __align__(16) unsigned short Bs[2 * 128 * 32];
  const int local = blockIdx.x & 255;
  const int wsz = (local & 7) * 32 + (local >> 3);
  const int nBase = (wsz & 7) * 128, mBase = (wsz >> 3) * 128;
  const int tid = threadIdx.x, lane = tid & 63;
  const int w = tid >> 6, wr = w >> 2, wc = w & 3;
  const int lr = lane & 15, lk = lane >> 4;

  const f32x4 fz = {0.f, 0.f, 0.f, 0.f};
  f32x4 acc[4][2];
#pragma unroll
  for (int i = 0; i < 4; i++)
#pragma unroll
    for (int j = 0; j < 2; j++) acc[i][j] = fz;

  gemm_core2(A, Bw, As, Bs, mBase, nBase, D_, tid, acc);

#pragma unroll
  for (int mi = 0; mi < 4; mi++)
#pragma unroll
    for (int ni = 0; ni < 2; ni++)
#pragma unroll
      for (int r = 0; r < 4; r++) {
        int gr = mBase + wr * 64 + mi * 16 + lk * 4 + r;
        int gc = nBase + wc * 32 + ni * 16 + lr;
        Cout[(size_t)gr * D_ + gc] = acc[mi][ni][r] + bias[gc];
      }
}

// -------- Flash attention over compacted keys + memory slots ------------------
// Block: 256 q-rows (8 waves x 32) for one (b,h). KV tile = 64 keys.
// Per lane: q = lane&31; P^T in registers; scores in log2 units (LOG2E in Q).
__global__ __launch_bounds__(512)
void attn_kernel(const unsigned short* __restrict__ Qb,
                 const unsigned short* __restrict__ Kb,
                 const unsigned short* __restrict__ VtG,
                 const int* __restrict__ cnt,
                 unsigned short* __restrict__ Xb) {
  __shared__ __align__(16) unsigned short Ks[64 * 64];   // [key][d]  swizzled
  __shared__ __align__(16) unsigned short Vs[64 * 64];   // [d][key]  swizzled

  const int tid = threadIdx.x, lane = tid & 63, w = tid >> 6;   // w: 0..7
  const int l31 = lane & 31, hh = lane >> 5;
  const int qt = blockIdx.x, h = blockIdx.y, b = blockIdx.z;

  const int total = cnt[b] + M_;            // live keys incl. memory slots
  const int nt = (total + 63) >> 6;         // tiles (<= 33)

  const int r0 = tid >> 3, c0 = tid & 7;          // staging: row 0..63, chunk 0..7
  const int ck = c0 ^ (r0 & 7);                   // swizzled chunk
  const unsigned short* Kg = Kb + (size_t)b * SKM * D_ + (size_t)h * HD_;
  const unsigned short* Vg = VtG + (size_t)(b * H_ + h) * HD_ * SKM;

  // Q fragments (B-operand of swapped QK^T): Q[q][ds*16 + hh*8 + i]
  const unsigned short* qp = Qb + ((size_t)(b * S_) + qt * 256 + w * 32 + l31) * D_ + h * HD_;
  s16x8 qf[4];
#pragma unroll
  for (int ds = 0; ds < 4; ds++) qf[ds] = *(const s16x8*)&qp[ds * 16 + hh * 8];

  f32x16 accO[2];
#pragma unroll
  for (int dt = 0; dt < 2; dt++)
#pragma unroll
    for (int j = 0; j < 16; j++) accO[dt][j] = 0.f;
  float m_r = -1e20f, l_r = 0.f;

  uint4 kr0, vr0;
  auto LOAD = [&](int kt) {   // rows < nt*64 <= 2112, always in-bounds
    kr0 = *(const uint4*)&Kg[(size_t)(kt * 64 + r0) * D_ + c0 * 8];
    vr0 = *(const uint4*)&Vg[(size_t)r0 * SKM + kt * 64 + c0 * 8];
  };
  LOAD(0);

  for (int kt = 0; kt < nt; ++kt) {
    __syncthreads();                 // previous tile's LDS reads complete
    *(uint4*)&Ks[r0 * 64 + ck * 8] = kr0;
    *(uint4*)&Vs[r0 * 64 + ck * 8] = vr0;
    __syncthreads();
    if (kt + 1 < nt) LOAD(kt + 1);   // prefetch hides HBM under compute

    // ---- S^T = K · Q^T : p0 = keys 0..31, p1 = keys 32..63 (lane: q=l31) ----
    f32x16 p0, p1;
#pragma unroll
    for (int j = 0; j < 16; j++) { p0[j] = 0.f; p1[j] = 0.f; }
    __builtin_amdgcn_s_setprio(1);
#pragma unroll
    for (int ds = 0; ds < 4; ds++) {
      s16x8 ka0 = *(const s16x8*)&Ks[l31 * 64 + (((ds * 2 + hh) ^ (l31 & 7)) << 3)];
      s16x8 ka1 = *(const s16x8*)&Ks[(32 + l31) * 64 + (((ds * 2 + hh) ^ (l31 & 7)) << 3)];
      p0 = __builtin_amdgcn_mfma_f32_32x32x16_bf16(ka0, qf[ds], p0, 0, 0, 0);
      p1 = __builtin_amdgcn_mfma_f32_32x32x16_bf16(ka1, qf[ds], p1, 0, 0, 0);
    }
    __builtin_amdgcn_s_setprio(0);

    // ---- tail tile: kill keys beyond `total` (key = (j&3)+8*(j>>2)+4*hh) ----
    if (kt == nt - 1) {
      int valid = total - kt * 64;   // 1..64
#pragma unroll
      for (int j = 0; j < 16; j++) {
        int kl = (j & 3) + 8 * (j >> 2) + 4 * hh;
        if (kl >= valid) p0[j] = -1e30f;
        if (kl + 32 >= valid) p1[j] = -1e30f;
      }
    }

    // ---- online softmax in log2 units, defer-max (T13, THR=8) ----
    float vmax = fmaxf(p0[0], p1[0]);
#pragma unroll
    for (int j = 1; j < 16; j++) vmax = fmaxf(vmax, fmaxf(p0[j], p1[j]));
    vmax = fmaxf(vmax, __shfl_xor(vmax, 32));
    if (!__all(vmax - m_r <= 8.0f)) {
      float mnew = fmaxf(m_r, vmax);
      float fac = __builtin_amdgcn_exp2f(m_r - mnew);
      m_r = mnew;
      l_r *= fac;
#pragma unroll
      for (int dt = 0; dt < 2; dt++)
#pragma unroll
        for (int j = 0; j < 16; j++) accO[dt][j] *= fac;
    }
    float sum = 0.f;
#pragma unroll
    for (int j = 0; j < 16; j++) {
      p0[j] = __builtin_amdgcn_exp2f(p0[j] - m_r); sum += p0[j];
      p1[j] = __builtin_amdgcn_exp2f(p1[j] - m_r); sum += p1[j];
    }
    sum += __shfl_xor(sum, 32);
    l_r += sum;

    // ---- build P^T fragments: frag[ks] = P[q][16ks + hh*8 + 0..7] as bf16x8 ----
    s16x8 pf_[4];
#pragma unroll
    for (int ks = 0; ks < 4; ks++) {
      const int base = (ks & 1) * 8;
#define ELT(t) ((ks >= 2) ? p1[base + (t)] : p0[base + (t)])
      unsigned w0 = pkbf(ELT(0), ELT(1));
      unsigned w1 = pkbf(ELT(2), ELT(3));
      unsigned w2 = pkbf(ELT(4), ELT(5));
      unsigned w3 = pkbf(ELT(6), ELT(7));
#undef ELT
      unsigned s0 = hh ? w0 : w2;         // h0 sends keys {8..11}, h1 sends {4..7}
      unsigned s1 = hh ? w1 : w3;
      unsigned g0 = (unsigned)__shfl_xor((int)s0, 32);
      unsigned g1 = (unsigned)__shfl_xor((int)s1, 32);
      union { s16x8 v; unsigned u[4]; } pf;
      pf.u[0] = hh ? g0 : w0;
      pf.u[1] = hh ? g1 : w1;
      pf.u[2] = hh ? w2 : g0;
      pf.u[3] = hh ? w3 : g1;
      pf_[ks] = pf.v;
    }

    // ---- O^T += V^T · P^T  (row d = dt*32+(j&3)+8*(j>>2)+4*hh, col q = l31) ----
    __builtin_amdgcn_s_setprio(1);
#pragma unroll
    for (int dt = 0; dt < 2; dt++)
#pragma unroll
      for (int ks = 0; ks < 4; ks++) {
        s16x8 va = *(const s16x8*)&Vs[(dt * 32 + l31) * 64 + (((ks * 2 + hh) ^ (l31 & 7)) << 3)];
        accO[dt] = __builtin_amdgcn_mfma_f32_32x32x16_bf16(va, pf_[ks], accO[dt], 0, 0, 0);
      }
    __builtin_amdgcn_s_setprio(0);
  }

  float invl = 1.0f / l_r;
  size_t orow = ((size_t)(b * S_) + qt * 256 + w * 32 + l31) * D_ + h * HD_;
#pragma unroll
  for (int dt = 0; dt < 2; dt++)
#pragma unroll
    for (int j = 0; j < 16; j++) {
      int d = dt * 32 + (j & 3) + 8 * (j >> 2) + 4 * hh;
      Xb[orow + d] = f2bf(accO[dt][j] * invl);
    }
}

// ------------------------------- launcher -------------------------------------
extern "C" void kernel_launch(void* const* d_in, const int* in_sizes, int n_in,
                              void* d_out, int out_size, void* d_ws, size_t ws_size,
                              hipStream_t stream) {
  const float* query = (const float*)d_in[0];
  const float* key   = (const float*)d_in[1];
  const float* value = (const float*)d_in[2];
  const int*   mask  = (const int*)d_in[3];
  const float* Wq    = (const float*)d_in[4];
  const float* bq    = (const float*)d_in[5];
  const float* Wk    = (const float*)d_in[6];
  const float* bk    = (const float*)d_in[7];
  const float* Wv    = (const float*)d_in[8];
  const float* bv    = (const float*)d_in[9];
  const float* Wo    = (const float*)d_in[10];
  const float* bo    = (const float*)d_in[11];
  const float* m_k   = (const float*)d_in[12];
  const float* m_v   = (const float*)d_in[13];

  const int NQ = B_ * S_ * D_;     // 4,194,304
  const int NW = D_ * D_;          // 1,048,576 = 2^20
  const int NK = B_ * SKM * D_;    // 4,325,376

  unsigned short* ws = (unsigned short*)d_ws;   // ~67.6 MB + 16 KB
  unsigned short* qf = ws;
  unsigned short* kf = qf + NQ;
  unsigned short* vf = kf + NQ;
  unsigned short* wq = vf + NQ;
  unsigned short* wk = wq + NW;
  unsigned short* wv = wk + NW;
  unsigned short* wo = wv + NW;
  unsigned short* Qb = wo + NW;
  unsigned short* Kb = Qb + NQ;
  unsigned short* Vt = Kb + NK;    // [b][h][d][key]
  unsigned short* Xb = Vt + NK;
  int* idx = (int*)(Xb + NQ);      // [B][S]
  int* cnt = idx + B_ * S_;        // [B]

  compact_mask<<<B_, 256, 0, stream>>>(mask, idx, cnt);
  // one launch: query+weights linear cvt (8192 blocks) + K/V gather (8192)
  cvt_fused<<<16384, 256, 0, stream>>>(query, Wq, Wk, Wv, Wo, key, value,
                                       qf, wq, wk, wv, wo, kf, vf, idx, cnt);

  // merged Q/K/V projection, 128x128 tiles, 8-wave blocks (wave-TLP latency hiding)
  gemm_qkv<<<768, 512, 0, stream>>>(qf, kf, vf, wq, wk, wv, bq, bk, bv, Qb, Kb, Vt, cnt);
  // memory rows appended at key position cnt[b] — must run AFTER K/V GEMMs
  fill_mem<<<(M_ * D_) / 256, 256, 0, stream>>>(m_k, m_v, Kb, Vt, cnt);

  attn_kernel<<<dim3(S_ / 256, H_, B_), 512, 0, stream>>>(Qb, Kb, Vt, cnt, Xb);

  gemm_o<<<256, 512, 0, stream>>>(Xb, wo, bo, (float*)d_out);
}